// Round 2
// 643.861 us; speedup vs baseline: 1.0015x; 1.0015x over previous
//
#include <hip/hip_runtime.h>
#include <hip/hip_fp16.h>

#define HEADS 8
#define F_IN 256
#define OUT 64
#define NOUT 512   // HEADS*OUT

typedef __attribute__((ext_vector_type(8))) _Float16 f16x8;
typedef __attribute__((ext_vector_type(2))) _Float16 f16x2;
typedef __attribute__((ext_vector_type(4))) float f32x4;

__device__ __forceinline__ short f2h(float f) {
  _Float16 h = (_Float16)f;
  return *(short*)&h;
}
__device__ __forceinline__ f16x2 u2h2(unsigned u) {
  union { unsigned u; f16x2 h; } x; x.u = u; return x.h;
}

// ---------------------------------------------------------------------------
// Convert f32 -> f16 bits, 8 elems/thread
// ---------------------------------------------------------------------------
__global__ __launch_bounds__(256) void conv_kernel(
    const float* __restrict__ src, short* __restrict__ dst, int n8)
{
  int i = blockIdx.x * 256 + threadIdx.x;
  if (i >= n8) return;
  const float4 a = *(const float4*)(src + (size_t)i * 8);
  const float4 b = *(const float4*)(src + (size_t)i * 8 + 4);
  short r[8] = { f2h(a.x), f2h(a.y), f2h(a.z), f2h(a.w),
                 f2h(b.x), f2h(b.y), f2h(b.z), f2h(b.w) };
  *(uint4*)(dst + (size_t)i * 8) = *(uint4*)r;
}

// ---------------------------------------------------------------------------
// MFMA GEMM (f16): t2[n][h*64+o] = dot(xh[n,:], W2[h*64+o,:]) -- NODE-MAJOR out.
// Block 256 thr = 4 waves; tile 128 rows x 64 cols (one head); BK=64.
// Fused epilogue: Ar[h][n] (Al cancels in row-softmax; never computed).
// ---------------------------------------------------------------------------
__global__ __launch_bounds__(256) void gemm_mfma(
    const short* __restrict__ xh, const short* __restrict__ W2,
    const float* __restrict__ As, const float* __restrict__ Asb,
    short* __restrict__ t2, float* __restrict__ Ar, int N)
{
  __shared__ __align__(16) short as[128][72];  // 144B row stride: 2-way bank alias (free)
  __shared__ __align__(16) short bs[64][72];
  const int tid = threadIdx.x;
  const int h  = blockIdx.x;            // col tile == head
  const int n0 = blockIdx.y * 128;
  const int lane = tid & 63, wave = tid >> 6;
  const int lcol = lane & 15, quad = lane >> 4;
  const int m0 = wave * 32;
  const short* Wh = W2 + h * OUT * F_IN;

  f32x4 acc[2][4] = {};

  for (int k0 = 0; k0 < F_IN; k0 += 64) {
    __syncthreads();
    // stage A: 128 rows x 8 slices(8 f16 = 16B); 1024 slices / 256 thr
    #pragma unroll
    for (int p = 0; p < 4; ++p) {
      int id = tid + 256 * p;
      int r = id >> 3, s = id & 7;
      int n = n0 + r;
      uint4 v = make_uint4(0, 0, 0, 0);
      if (n < N) v = *(const uint4*)(xh + (size_t)n * F_IN + k0 + s * 8);
      *(uint4*)&as[r][s * 8] = v;
    }
    // stage B: 64 rows x 8 slices
    #pragma unroll
    for (int p = 0; p < 2; ++p) {
      int id = tid + 256 * p;
      int r = id >> 3, s = id & 7;
      uint4 v = *(const uint4*)(Wh + r * F_IN + k0 + s * 8);
      *(uint4*)&bs[r][s * 8] = v;
    }
    __syncthreads();
    #pragma unroll
    for (int ks = 0; ks < 2; ++ks) {
      f16x8 af[2], bf[4];
      #pragma unroll
      for (int i = 0; i < 2; ++i)
        af[i] = *(const f16x8*)&as[m0 + i * 16 + lcol][ks * 32 + quad * 8];
      #pragma unroll
      for (int j = 0; j < 4; ++j)
        bf[j] = *(const f16x8*)&bs[j * 16 + lcol][ks * 32 + quad * 8];
      #pragma unroll
      for (int i = 0; i < 2; ++i)
        #pragma unroll
        for (int j = 0; j < 4; ++j)
          acc[i][j] = __builtin_amdgcn_mfma_f32_16x16x32_f16(
              af[i], bf[j], acc[i][j], 0, 0, 0);
    }
  }

  // epilogue: t2 (f16, node-major) + fused Ar
  float arw_l[4];
  #pragma unroll
  for (int j = 0; j < 4; ++j) arw_l[j] = As[h * 2 * OUT + OUT + j * 16 + lcol];
  const float arb = Asb[h * 2 + 1];
  #pragma unroll
  for (int i = 0; i < 2; ++i) {
    #pragma unroll
    for (int reg = 0; reg < 4; ++reg) {
      int n = n0 + m0 + i * 16 + quad * 4 + reg;
      float p = 0.f;
      #pragma unroll
      for (int j = 0; j < 4; ++j) p = fmaf(acc[i][j][reg], arw_l[j], p);
      #pragma unroll
      for (int off = 1; off < 16; off <<= 1) p += __shfl_xor(p, off);
      if (n < N) {
        if (lcol == 0) Ar[(size_t)h * N + n] = p + arb;
        short* trow = t2 + (size_t)n * NOUT + h * OUT;
        #pragma unroll
        for (int j = 0; j < 4; ++j) trow[j * 16 + lcol] = f2h(acc[i][j][reg]);
      }
    }
  }
}

// ---------------------------------------------------------------------------
// CSR build: histogram -> 3-phase multi-block scan -> counting-sort scatter
// ---------------------------------------------------------------------------
#define SB 128

__global__ void hist_kernel(const int* __restrict__ row, int* __restrict__ deg, int E)
{
  int e = blockIdx.x * 256 + threadIdx.x;
  if (e < E) atomicAdd(&deg[row[e]], 1);
}

__global__ __launch_bounds__(256) void scan1_kernel(
    const int* __restrict__ deg, int* __restrict__ bsum, int N)
{
  const int b = blockIdx.x;
  const int C = (N + SB - 1) / SB;
  const int base = b * C;
  int s = 0;
  for (int i = threadIdx.x; i < C; i += 256) {
    int idx = base + i;
    if (idx < N) s += deg[idx];
  }
  #pragma unroll
  for (int off = 32; off >= 1; off >>= 1) s += __shfl_xor(s, off);
  __shared__ int sm[4];
  if ((threadIdx.x & 63) == 0) sm[threadIdx.x >> 6] = s;
  __syncthreads();
  if (threadIdx.x == 0) bsum[b] = sm[0] + sm[1] + sm[2] + sm[3];
}

__global__ __launch_bounds__(SB) void scan2_kernel(
    const int* __restrict__ bsum, int* __restrict__ bofs, int* __restrict__ total)
{
  __shared__ int sd[SB];
  const int t = threadIdx.x;
  int v = bsum[t];
  sd[t] = v;
  __syncthreads();
  for (int off = 1; off < SB; off <<= 1) {
    int u = (t >= off) ? sd[t - off] : 0;
    __syncthreads();
    sd[t] += u;
    __syncthreads();
  }
  bofs[t] = sd[t] - v;
  if (t == SB - 1) total[0] = sd[t];
}

__global__ __launch_bounds__(256) void scan3_kernel(
    const int* __restrict__ deg, const int* __restrict__ bofs,
    int* __restrict__ row_ptr, int N)
{
  const int b = blockIdx.x;
  const int C = (N + SB - 1) / SB;
  const int CH = (C + 255) / 256;
  const int base = b * C;
  const int lim = min(base + C, N);
  const int start = base + threadIdx.x * CH;
  int vals[4];
  int s = 0;
  for (int i = 0; i < CH; ++i) {
    int idx = start + i;
    vals[i] = (idx < lim) ? deg[idx] : 0;
    s += vals[i];
  }
  __shared__ int sd[256];
  sd[threadIdx.x] = s;
  __syncthreads();
  for (int off = 1; off < 256; off <<= 1) {
    int u = (threadIdx.x >= off) ? sd[threadIdx.x - off] : 0;
    __syncthreads();
    sd[threadIdx.x] += u;
    __syncthreads();
  }
  int excl = sd[threadIdx.x] - s + bofs[b];
  for (int i = 0; i < CH; ++i) {
    int idx = start + i;
    if (idx < lim) { row_ptr[idx] = excl; excl += vals[i]; }
  }
}

__global__ void scatter_kernel(const int* __restrict__ row, const int* __restrict__ col,
                               const int* __restrict__ row_ptr, int* __restrict__ cursor,
                               int* __restrict__ col_sorted, int E)
{
  int e = blockIdx.x * 256 + threadIdx.x;
  if (e < E) {
    int r = row[e];
    int pos = atomicAdd(&cursor[r], 1);
    col_sorted[row_ptr[r] + pos] = col[e];
  }
}

// ---------------------------------------------------------------------------
// Per-head global max of Ar, then Wh16[n][h] = f16(exp(Ar-mh)).
// (Per-row max redundant: softmax shift-invariant; Ar ~ N(0,1) so exp range
//  [e^-9, 1] -- comfortably inside f16 normals.)
// ---------------------------------------------------------------------------
__global__ __launch_bounds__(256) void maxred_kernel(
    const float* __restrict__ Ar, float* __restrict__ m, int N)
{
  const int h = blockIdx.x;
  const float* a = Ar + (size_t)h * N;
  float mm = -1e30f;
  for (int i = threadIdx.x; i < N; i += 256) mm = fmaxf(mm, a[i]);
  #pragma unroll
  for (int off = 32; off >= 1; off >>= 1) mm = fmaxf(mm, __shfl_xor(mm, off));
  __shared__ float sm[4];
  if ((threadIdx.x & 63) == 0) sm[threadIdx.x >> 6] = mm;
  __syncthreads();
  if (threadIdx.x == 0)
    m[h] = fmaxf(fmaxf(sm[0], sm[1]), fmaxf(sm[2], sm[3]));
}

__global__ __launch_bounds__(256) void expw_kernel(
    const float* __restrict__ Ar, const float* __restrict__ m,
    unsigned short* __restrict__ Wh16, int N)
{
  const int n = blockIdx.x * 256 + threadIdx.x;
  const int h = blockIdx.y;
  if (n < N) {
    float w = __expf(Ar[(size_t)h * N + n] - m[h]);
    Wh16[(size_t)n * HEADS + h] = (unsigned short)f2h(w);
  }
}

// ---------------------------------------------------------------------------
// Aggregation: ONE wave per row, ALL 8 heads fused.
// lane l = (head = l>>3, octet = l&7) owns output elements [8l, 8l+8).
// Per edge the 64 lanes read one contiguous 1KB t2 row. Edges processed in
// PAIRS: v_perm_b32 interleaves (t_e1[i], t_e2[i]) and v_dot2_f32_f16
// accumulates both edges in one instruction (dot2's pair-reduction axis ==
// the edge axis). No cross-lane epilogue reduction needed at all.
// ---------------------------------------------------------------------------
__global__ __launch_bounds__(256) void agg_kernel(
    const int* __restrict__ row_ptr, const int* __restrict__ col_sorted,
    const unsigned short* __restrict__ Wh16, const unsigned short* __restrict__ t2,
    const float* __restrict__ Wb, float* __restrict__ out, int N)
{
  const int lane = threadIdx.x & 63;
  const int wave = threadIdx.x >> 6;
  const int row = blockIdx.x * 4 + wave;
  if (row >= N) return;
  const int head = lane >> 3;
  const int start = row_ptr[row], end = row_ptr[row + 1];

  float acc[8];
  #pragma unroll
  for (int i = 0; i < 8; ++i) acc[i] = 0.f;
  float sw = 0.f;
  const f16x2 ones = {(_Float16)1.0f, (_Float16)1.0f};

  int e = start;
  int c1 = 0, c2 = 0;
  if (e < end) {
    c1 = col_sorted[e];
    c2 = (e + 1 < end) ? col_sorted[e + 1] : c1;
  }
  while (e < end) {
    const int has2 = (e + 1 < end);
    const int en = e + 2;
    // prefetch next pair's cols (sequential, L1-resident) before the gathers
    int n1 = 0, n2 = 0;
    if (en < end) {
      n1 = col_sorted[en];
      n2 = (en + 1 < end) ? col_sorted[en + 1] : n1;
    }
    unsigned w1 = Wh16[(size_t)c1 * HEADS + head];
    unsigned w2 = has2 ? (unsigned)Wh16[(size_t)c2 * HEADS + head] : 0u;
    const uint4 v1 = *(const uint4*)(t2 + (size_t)c1 * NOUT + lane * 8);
    const uint4 v2 = *(const uint4*)(t2 + (size_t)c2 * NOUT + lane * 8);
    const unsigned wp = w1 | (w2 << 16);
    const f16x2 wpr = u2h2(wp);
    sw = __builtin_amdgcn_fdot2(wpr, ones, sw, false);
    unsigned a1[4] = { v1.x, v1.y, v1.z, v1.w };
    unsigned a2[4] = { v2.x, v2.y, v2.z, v2.w };
    #pragma unroll
    for (int q = 0; q < 4; ++q) {
      // (t_e1[2q], t_e2[2q]) and (t_e1[2q+1], t_e2[2q+1])
      unsigned plo = __builtin_amdgcn_perm(a2[q], a1[q], 0x05040100u);
      unsigned phi = __builtin_amdgcn_perm(a2[q], a1[q], 0x07060302u);
      acc[2 * q]     = __builtin_amdgcn_fdot2(wpr, u2h2(plo), acc[2 * q], false);
      acc[2 * q + 1] = __builtin_amdgcn_fdot2(wpr, u2h2(phi), acc[2 * q + 1], false);
    }
    c1 = n1; c2 = n2; e = en;
  }

  const float inv = (sw > 0.f) ? 1.f / sw : 0.f;
  const float4 b0 = *(const float4*)(Wb + lane * 8);
  const float4 b1 = *(const float4*)(Wb + lane * 8 + 4);
  const float bb[8] = { b0.x, b0.y, b0.z, b0.w, b1.x, b1.y, b1.z, b1.w };
  float r[8];
  #pragma unroll
  for (int i = 0; i < 8; ++i) {
    float y = acc[i] * inv + bb[i];
    r[i] = (y > 0.f) ? y : (__expf(y) - 1.f);
  }
  float* op = out + (size_t)row * NOUT + lane * 8;
  *(float4*)op       = make_float4(r[0], r[1], r[2], r[3]);
  *((float4*)op + 1) = make_float4(r[4], r[5], r[6], r[7]);
}

// ---------------------------------------------------------------------------
extern "C" void kernel_launch(void* const* d_in, const int* in_sizes, int n_in,
                              void* d_out, int out_size, void* d_ws, size_t ws_size,
                              hipStream_t stream)
{
  const float* x    = (const float*)d_in[0];
  const int*   erow = (const int*)d_in[1];
  const int*   ecol = (const int*)d_in[2];
  const float* Ws   = (const float*)d_in[3];
  const float* Wb   = (const float*)d_in[4];
  const float* As   = (const float*)d_in[5];
  const float* Asb  = (const float*)d_in[6];
  float* out = (float*)d_out;
  const int N = in_sizes[0] / F_IN;
  const int E = in_sizes[1];

  char* p = (char*)d_ws;
  short* t2      = (short*)p; p += (size_t)HEADS * N * OUT * sizeof(short);
  short* xh      = (short*)p; p += (size_t)N * F_IN * sizeof(short);
  short* W2      = (short*)p; p += (size_t)NOUT * F_IN * sizeof(short);
  float* Ar      = (float*)p; p += (size_t)HEADS * N * sizeof(float);
  unsigned short* Wh16 = (unsigned short*)p; p += (size_t)N * HEADS * sizeof(short);
  float* mbuf    = (float*)p; p += 64 * sizeof(float);
  int* row_ptr   = (int*)p;   p += (size_t)(N + 1) * sizeof(int);
  int* deg       = (int*)p;   p += (size_t)N * sizeof(int);   // deg+cursor adjacent:
  int* cursor    = (int*)p;   p += (size_t)N * sizeof(int);   // one memset covers both
  int* bsum      = (int*)p;   p += SB * sizeof(int);
  int* bofs      = (int*)p;   p += SB * sizeof(int);
  int* col_sorted= (int*)p;   p += (size_t)E * sizeof(int);

  hipMemsetAsync(deg, 0, (size_t)2 * N * sizeof(int), stream);

  // CSR build
  hist_kernel<<<dim3((E + 255) / 256), dim3(256), 0, stream>>>(erow, deg, E);
  scan1_kernel<<<dim3(SB), dim3(256), 0, stream>>>(deg, bsum, N);
  scan2_kernel<<<dim3(1), dim3(SB), 0, stream>>>(bsum, bofs, row_ptr + N);
  scan3_kernel<<<dim3(SB), dim3(256), 0, stream>>>(deg, bofs, row_ptr, N);
  scatter_kernel<<<dim3((E + 255) / 256), dim3(256), 0, stream>>>(
      erow, ecol, row_ptr, cursor, col_sorted, E);

  // f16 conversions
  conv_kernel<<<dim3((N * F_IN / 8 + 255) / 256), dim3(256), 0, stream>>>(
      x, xh, N * F_IN / 8);
  conv_kernel<<<dim3((NOUT * F_IN / 8 + 255) / 256), dim3(256), 0, stream>>>(
      Ws, W2, NOUT * F_IN / 8);

  // MFMA GEMM + fused Ar (node-major t2 output)
  dim3 gg(HEADS, (N + 127) / 128);
  gemm_mfma<<<gg, dim3(256), 0, stream>>>(xh, W2, As, Asb, t2, Ar, N);

  maxred_kernel<<<dim3(HEADS), dim3(256), 0, stream>>>(Ar, mbuf, N);
  dim3 ge((N + 255) / 256, HEADS);
  expw_kernel<<<ge, dim3(256), 0, stream>>>(Ar, mbuf, Wh16, N);

  // fused-head aggregation: one wave per row
  agg_kernel<<<dim3((N + 3) / 4), dim3(256), 0, stream>>>(
      row_ptr, col_sorted, Wh16, (const unsigned short*)t2, Wb, out, N);
}

// Round 3
// 626.295 us; speedup vs baseline: 1.0296x; 1.0280x over previous
//
#include <hip/hip_runtime.h>
#include <hip/hip_fp16.h>

#define HEADS 8
#define F_IN 256
#define OUT 64
#define NOUT 512   // HEADS*OUT

typedef __attribute__((ext_vector_type(8))) _Float16 f16x8;
typedef __attribute__((ext_vector_type(2))) _Float16 f16x2;
typedef __attribute__((ext_vector_type(4))) float f32x4;

__device__ __forceinline__ short f2h(float f) {
  _Float16 h = (_Float16)f;
  return *(short*)&h;
}
__device__ __forceinline__ f16x2 u2h2(unsigned u) {
  union { unsigned u; f16x2 h; } x; x.u = u; return x.h;
}

// ---------------------------------------------------------------------------
// Convert f32 -> f16 bits, 8 elems/thread
// ---------------------------------------------------------------------------
__global__ __launch_bounds__(256) void conv_kernel(
    const float* __restrict__ src, short* __restrict__ dst, int n8)
{
  int i = blockIdx.x * 256 + threadIdx.x;
  if (i >= n8) return;
  const float4 a = *(const float4*)(src + (size_t)i * 8);
  const float4 b = *(const float4*)(src + (size_t)i * 8 + 4);
  short r[8] = { f2h(a.x), f2h(a.y), f2h(a.z), f2h(a.w),
                 f2h(b.x), f2h(b.y), f2h(b.z), f2h(b.w) };
  *(uint4*)(dst + (size_t)i * 8) = *(uint4*)r;
}

// ---------------------------------------------------------------------------
// MFMA GEMM (f16): t2[n][h*64+o] = dot(xh[n,:], W2[h*64+o,:]) -- NODE-MAJOR out.
// Block 256 thr = 4 waves; tile 128 rows x 64 cols (one head); BK=64.
// Fused epilogue: Ar[h][n] (Al cancels in row-softmax; never computed).
// ---------------------------------------------------------------------------
__global__ __launch_bounds__(256) void gemm_mfma(
    const short* __restrict__ xh, const short* __restrict__ W2,
    const float* __restrict__ As, const float* __restrict__ Asb,
    short* __restrict__ t2, float* __restrict__ Ar, int N)
{
  __shared__ __align__(16) short as[128][72];  // 144B row stride: 2-way bank alias (free)
  __shared__ __align__(16) short bs[64][72];
  const int tid = threadIdx.x;
  const int h  = blockIdx.x;            // col tile == head
  const int n0 = blockIdx.y * 128;
  const int lane = tid & 63, wave = tid >> 6;
  const int lcol = lane & 15, quad = lane >> 4;
  const int m0 = wave * 32;
  const short* Wh = W2 + h * OUT * F_IN;

  f32x4 acc[2][4] = {};

  for (int k0 = 0; k0 < F_IN; k0 += 64) {
    __syncthreads();
    // stage A: 128 rows x 8 slices(8 f16 = 16B); 1024 slices / 256 thr
    #pragma unroll
    for (int p = 0; p < 4; ++p) {
      int id = tid + 256 * p;
      int r = id >> 3, s = id & 7;
      int n = n0 + r;
      uint4 v = make_uint4(0, 0, 0, 0);
      if (n < N) v = *(const uint4*)(xh + (size_t)n * F_IN + k0 + s * 8);
      *(uint4*)&as[r][s * 8] = v;
    }
    // stage B: 64 rows x 8 slices
    #pragma unroll
    for (int p = 0; p < 2; ++p) {
      int id = tid + 256 * p;
      int r = id >> 3, s = id & 7;
      uint4 v = *(const uint4*)(Wh + r * F_IN + k0 + s * 8);
      *(uint4*)&bs[r][s * 8] = v;
    }
    __syncthreads();
    #pragma unroll
    for (int ks = 0; ks < 2; ++ks) {
      f16x8 af[2], bf[4];
      #pragma unroll
      for (int i = 0; i < 2; ++i)
        af[i] = *(const f16x8*)&as[m0 + i * 16 + lcol][ks * 32 + quad * 8];
      #pragma unroll
      for (int j = 0; j < 4; ++j)
        bf[j] = *(const f16x8*)&bs[j * 16 + lcol][ks * 32 + quad * 8];
      #pragma unroll
      for (int i = 0; i < 2; ++i)
        #pragma unroll
        for (int j = 0; j < 4; ++j)
          acc[i][j] = __builtin_amdgcn_mfma_f32_16x16x32_f16(
              af[i], bf[j], acc[i][j], 0, 0, 0);
    }
  }

  // epilogue: t2 (f16, node-major) + fused Ar
  float arw_l[4];
  #pragma unroll
  for (int j = 0; j < 4; ++j) arw_l[j] = As[h * 2 * OUT + OUT + j * 16 + lcol];
  const float arb = Asb[h * 2 + 1];
  #pragma unroll
  for (int i = 0; i < 2; ++i) {
    #pragma unroll
    for (int reg = 0; reg < 4; ++reg) {
      int n = n0 + m0 + i * 16 + quad * 4 + reg;
      float p = 0.f;
      #pragma unroll
      for (int j = 0; j < 4; ++j) p = fmaf(acc[i][j][reg], arw_l[j], p);
      #pragma unroll
      for (int off = 1; off < 16; off <<= 1) p += __shfl_xor(p, off);
      if (n < N) {
        if (lcol == 0) Ar[(size_t)h * N + n] = p + arb;
        short* trow = t2 + (size_t)n * NOUT + h * OUT;
        #pragma unroll
        for (int j = 0; j < 4; ++j) trow[j * 16 + lcol] = f2h(acc[i][j][reg]);
      }
    }
  }
}

// ---------------------------------------------------------------------------
// CSR build: histogram -> 3-phase multi-block scan -> counting-sort scatter
// ---------------------------------------------------------------------------
#define SB 128

__global__ void hist_kernel(const int* __restrict__ row, int* __restrict__ deg, int E)
{
  int e = blockIdx.x * 256 + threadIdx.x;
  if (e < E) atomicAdd(&deg[row[e]], 1);
}

__global__ __launch_bounds__(256) void scan1_kernel(
    const int* __restrict__ deg, int* __restrict__ bsum, int N)
{
  const int b = blockIdx.x;
  const int C = (N + SB - 1) / SB;
  const int base = b * C;
  int s = 0;
  for (int i = threadIdx.x; i < C; i += 256) {
    int idx = base + i;
    if (idx < N) s += deg[idx];
  }
  #pragma unroll
  for (int off = 32; off >= 1; off >>= 1) s += __shfl_xor(s, off);
  __shared__ int sm[4];
  if ((threadIdx.x & 63) == 0) sm[threadIdx.x >> 6] = s;
  __syncthreads();
  if (threadIdx.x == 0) bsum[b] = sm[0] + sm[1] + sm[2] + sm[3];
}

__global__ __launch_bounds__(SB) void scan2_kernel(
    const int* __restrict__ bsum, int* __restrict__ bofs, int* __restrict__ total)
{
  __shared__ int sd[SB];
  const int t = threadIdx.x;
  int v = bsum[t];
  sd[t] = v;
  __syncthreads();
  for (int off = 1; off < SB; off <<= 1) {
    int u = (t >= off) ? sd[t - off] : 0;
    __syncthreads();
    sd[t] += u;
    __syncthreads();
  }
  bofs[t] = sd[t] - v;
  if (t == SB - 1) total[0] = sd[t];
}

__global__ __launch_bounds__(256) void scan3_kernel(
    const int* __restrict__ deg, const int* __restrict__ bofs,
    int* __restrict__ row_ptr, int N)
{
  const int b = blockIdx.x;
  const int C = (N + SB - 1) / SB;
  const int CH = (C + 255) / 256;
  const int base = b * C;
  const int lim = min(base + C, N);
  const int start = base + threadIdx.x * CH;
  int vals[4];
  int s = 0;
  for (int i = 0; i < CH; ++i) {
    int idx = start + i;
    vals[i] = (idx < lim) ? deg[idx] : 0;
    s += vals[i];
  }
  __shared__ int sd[256];
  sd[threadIdx.x] = s;
  __syncthreads();
  for (int off = 1; off < 256; off <<= 1) {
    int u = (threadIdx.x >= off) ? sd[threadIdx.x - off] : 0;
    __syncthreads();
    sd[threadIdx.x] += u;
    __syncthreads();
  }
  int excl = sd[threadIdx.x] - s + bofs[b];
  for (int i = 0; i < CH; ++i) {
    int idx = start + i;
    if (idx < lim) { row_ptr[idx] = excl; excl += vals[i]; }
  }
}

__global__ void scatter_kernel(const int* __restrict__ row, const int* __restrict__ col,
                               const int* __restrict__ row_ptr, int* __restrict__ cursor,
                               int* __restrict__ col_sorted, int E)
{
  int e = blockIdx.x * 256 + threadIdx.x;
  if (e < E) {
    int r = row[e];
    int pos = atomicAdd(&cursor[r], 1);
    col_sorted[row_ptr[r] + pos] = col[e];
  }
}

// ---------------------------------------------------------------------------
// Per-head global max of Ar, then Wh16[n][h] = f16(exp(Ar-mh)).
// ---------------------------------------------------------------------------
__global__ __launch_bounds__(256) void maxred_kernel(
    const float* __restrict__ Ar, float* __restrict__ m, int N)
{
  const int h = blockIdx.x;
  const float* a = Ar + (size_t)h * N;
  float mm = -1e30f;
  for (int i = threadIdx.x; i < N; i += 256) mm = fmaxf(mm, a[i]);
  #pragma unroll
  for (int off = 32; off >= 1; off >>= 1) mm = fmaxf(mm, __shfl_xor(mm, off));
  __shared__ float sm[4];
  if ((threadIdx.x & 63) == 0) sm[threadIdx.x >> 6] = mm;
  __syncthreads();
  if (threadIdx.x == 0)
    m[h] = fmaxf(fmaxf(sm[0], sm[1]), fmaxf(sm[2], sm[3]));
}

// coalesced: tid -> (n = i>>3, h = i&7), writes are contiguous 2B stream.
__global__ __launch_bounds__(256) void expw_kernel(
    const float* __restrict__ Ar, const float* __restrict__ m,
    unsigned short* __restrict__ Wh16, int N)
{
  const int i = blockIdx.x * 256 + threadIdx.x;
  if (i >= N * HEADS) return;
  const int n = i >> 3, h = i & 7;
  float w = __expf(Ar[(size_t)h * N + n] - m[h]);
  Wh16[i] = (unsigned short)f2h(w);
}

// ---------------------------------------------------------------------------
// Aggregation: ONE wave per row, ALL 8 heads fused; lane l owns out[8l..8l+8).
// Software-pipelined depth-2 ping-pong, 4 edges/stage: 8 uint4 t2-gathers in
// flight per wave (latency-bound fix). Tails are branch-free: column index
// clamped to end-1, weight cndmask'd to 0, stage count rounded up to even --
// a masked stage contributes exactly 0.
// ---------------------------------------------------------------------------
__global__ __launch_bounds__(256) void agg_kernel(
    const int* __restrict__ row_ptr, const int* __restrict__ col_sorted,
    const unsigned short* __restrict__ Wh16, const unsigned short* __restrict__ t2,
    const float* __restrict__ Wb, float* __restrict__ out, int N)
{
  const int lane = threadIdx.x & 63;
  const int wave = threadIdx.x >> 6;
  const int row = blockIdx.x * 4 + wave;
  if (row >= N) return;
  const int head = lane >> 3;
  const int start = row_ptr[row], end = row_ptr[row + 1];

  float acc[8];
  #pragma unroll
  for (int i = 0; i < 8; ++i) acc[i] = 0.f;
  float sw = 0.f;
  const f16x2 ones = {(_Float16)1.0f, (_Float16)1.0f};

  auto loadc = [&](int eb, int* c) {
    const int last = end - 1;
    #pragma unroll
    for (int k = 0; k < 4; ++k) {
      int idx = eb + k;
      idx = (idx < last) ? idx : last;
      c[k] = col_sorted[idx];
    }
  };
  auto issue = [&](int eb, const int* c, uint4* v, unsigned* w) {
    #pragma unroll
    for (int k = 0; k < 4; ++k) {
      unsigned wl = Wh16[(size_t)c[k] * HEADS + head];
      v[k] = *(const uint4*)(t2 + (size_t)c[k] * NOUT + (lane << 3));
      w[k] = (eb + k < end) ? wl : 0u;
    }
  };
  auto consume = [&](const uint4* v, const unsigned* w) {
    #pragma unroll
    for (int p = 0; p < 2; ++p) {
      const unsigned wp = w[2 * p] | (w[2 * p + 1] << 16);
      const f16x2 wpr = u2h2(wp);
      sw = __builtin_amdgcn_fdot2(wpr, ones, sw, false);
      unsigned a1[4] = { v[2 * p].x, v[2 * p].y, v[2 * p].z, v[2 * p].w };
      unsigned a2[4] = { v[2 * p + 1].x, v[2 * p + 1].y, v[2 * p + 1].z, v[2 * p + 1].w };
      #pragma unroll
      for (int q = 0; q < 4; ++q) {
        unsigned plo = __builtin_amdgcn_perm(a2[q], a1[q], 0x05040100u);
        unsigned phi = __builtin_amdgcn_perm(a2[q], a1[q], 0x07060302u);
        acc[2 * q]     = __builtin_amdgcn_fdot2(wpr, u2h2(plo), acc[2 * q],     false);
        acc[2 * q + 1] = __builtin_amdgcn_fdot2(wpr, u2h2(phi), acc[2 * q + 1], false);
      }
    }
  };

  const int deg = end - start;
  if (deg > 0) {
    const int nit  = (deg + 3) >> 2;    // 4-edge stages
    const int nit2 = (nit + 1) & ~1;    // round up to even (>=2)
    int cA[4], cB[4];
    uint4 vA[4], vB[4];
    unsigned wA[4], wB[4];
    loadc(start, cA);     issue(start, cA, vA, wA);
    loadc(start + 4, cB); issue(start + 4, cB, vB, wB);
    int e = start + 8;
    for (int s = 2; s < nit2; s += 2, e += 8) {
      consume(vA, wA);
      loadc(e, cA);     issue(e, cA, vA, wA);
      consume(vB, wB);
      loadc(e + 4, cB); issue(e + 4, cB, vB, wB);
    }
    consume(vA, wA);
    consume(vB, wB);
  }

  const float inv = (sw > 0.f) ? 1.f / sw : 0.f;
  const float4 b0 = *(const float4*)(Wb + lane * 8);
  const float4 b1 = *(const float4*)(Wb + lane * 8 + 4);
  const float bb[8] = { b0.x, b0.y, b0.z, b0.w, b1.x, b1.y, b1.z, b1.w };
  float r[8];
  #pragma unroll
  for (int i = 0; i < 8; ++i) {
    float y = acc[i] * inv + bb[i];
    r[i] = (y > 0.f) ? y : (__expf(y) - 1.f);
  }
  float* op = out + (size_t)row * NOUT + lane * 8;
  *(float4*)op       = make_float4(r[0], r[1], r[2], r[3]);
  *((float4*)op + 1) = make_float4(r[4], r[5], r[6], r[7]);
}

// ---------------------------------------------------------------------------
extern "C" void kernel_launch(void* const* d_in, const int* in_sizes, int n_in,
                              void* d_out, int out_size, void* d_ws, size_t ws_size,
                              hipStream_t stream)
{
  const float* x    = (const float*)d_in[0];
  const int*   erow = (const int*)d_in[1];
  const int*   ecol = (const int*)d_in[2];
  const float* Ws   = (const float*)d_in[3];
  const float* Wb   = (const float*)d_in[4];
  const float* As   = (const float*)d_in[5];
  const float* Asb  = (const float*)d_in[6];
  float* out = (float*)d_out;
  const int N = in_sizes[0] / F_IN;
  const int E = in_sizes[1];

  char* p = (char*)d_ws;
  short* t2      = (short*)p; p += (size_t)HEADS * N * OUT * sizeof(short);
  short* xh      = (short*)p; p += (size_t)N * F_IN * sizeof(short);
  short* W2      = (short*)p; p += (size_t)NOUT * F_IN * sizeof(short);
  float* Ar      = (float*)p; p += (size_t)HEADS * N * sizeof(float);
  unsigned short* Wh16 = (unsigned short*)p; p += (size_t)N * HEADS * sizeof(short);
  float* mbuf    = (float*)p; p += 64 * sizeof(float);
  int* row_ptr   = (int*)p;   p += (size_t)(N + 1) * sizeof(int);
  int* deg       = (int*)p;   p += (size_t)N * sizeof(int);   // deg+cursor adjacent:
  int* cursor    = (int*)p;   p += (size_t)N * sizeof(int);   // one memset covers both
  int* bsum      = (int*)p;   p += SB * sizeof(int);
  int* bofs      = (int*)p;   p += SB * sizeof(int);
  int* col_sorted= (int*)p;   p += (size_t)E * sizeof(int);

  hipMemsetAsync(deg, 0, (size_t)2 * N * sizeof(int), stream);

  // CSR build
  hist_kernel<<<dim3((E + 255) / 256), dim3(256), 0, stream>>>(erow, deg, E);
  scan1_kernel<<<dim3(SB), dim3(256), 0, stream>>>(deg, bsum, N);
  scan2_kernel<<<dim3(1), dim3(SB), 0, stream>>>(bsum, bofs, row_ptr + N);
  scan3_kernel<<<dim3(SB), dim3(256), 0, stream>>>(deg, bofs, row_ptr, N);
  scatter_kernel<<<dim3((E + 255) / 256), dim3(256), 0, stream>>>(
      erow, ecol, row_ptr, cursor, col_sorted, E);

  // f16 conversions
  conv_kernel<<<dim3((N * F_IN / 8 + 255) / 256), dim3(256), 0, stream>>>(
      x, xh, N * F_IN / 8);
  conv_kernel<<<dim3((NOUT * F_IN / 8 + 255) / 256), dim3(256), 0, stream>>>(
      Ws, W2, NOUT * F_IN / 8);

  // MFMA GEMM + fused Ar (node-major t2 output)
  dim3 gg(HEADS, (N + 127) / 128);
  gemm_mfma<<<gg, dim3(256), 0, stream>>>(xh, W2, As, Asb, t2, Ar, N);

  maxred_kernel<<<dim3(HEADS), dim3(256), 0, stream>>>(Ar, mbuf, N);
  expw_kernel<<<dim3((N * HEADS + 255) / 256), dim3(256), 0, stream>>>(
      Ar, mbuf, Wh16, N);

  // fused-head aggregation: one wave per row
  agg_kernel<<<dim3((N + 3) / 4), dim3(256), 0, stream>>>(
      row_ptr, col_sorted, Wh16, (const unsigned short*)t2, Wb, out, N);
}